// Round 1
// baseline (224.750 us; speedup 1.0000x reference)
//
#include <hip/hip_runtime.h>

#define B_    4
#define C_    256
#define Kk    7
#define GC_   16
#define G_    16
#define RED_  64
#define H_    56
#define W_    56
#define HW_   (H_ * W_)      // 3136
#define KK_   49             // K*K
#define KG_   784            // K*K*G

// Stage 1: t[b,o,p] = relu( sum_c w1[o,c] * x[b,c,p] + b1[o] )
// grid (49, 16, 4), block 64. Each thread: one pixel, 4 'o' outputs.
__global__ void gen1_kernel(const float* __restrict__ x,
                            const float* __restrict__ w1,
                            const float* __restrict__ b1,
                            float* __restrict__ t) {
    const int p  = blockIdx.x * 64 + threadIdx.x;  // 0..3135
    const int o0 = blockIdx.y * 4;
    const int b  = blockIdx.z;
    const float* xb = x + (size_t)b * C_ * HW_ + p;
    const float* w1a = w1 + (size_t)(o0 + 0) * C_;
    const float* w1b = w1 + (size_t)(o0 + 1) * C_;
    const float* w1c = w1 + (size_t)(o0 + 2) * C_;
    const float* w1d = w1 + (size_t)(o0 + 3) * C_;
    float a0 = 0.f, a1 = 0.f, a2 = 0.f, a3 = 0.f;
#pragma unroll 8
    for (int c = 0; c < C_; ++c) {
        const float xv = xb[(size_t)c * HW_];
        a0 += w1a[c] * xv;
        a1 += w1b[c] * xv;
        a2 += w1c[c] * xv;
        a3 += w1d[c] * xv;
    }
    float* tb = t + ((size_t)b * RED_ + o0) * HW_ + p;
    tb[0 * HW_] = fmaxf(a0 + b1[o0 + 0], 0.f);
    tb[1 * HW_] = fmaxf(a1 + b1[o0 + 1], 0.f);
    tb[2 * HW_] = fmaxf(a2 + b1[o0 + 2], 0.f);
    tb[3 * HW_] = fmaxf(a3 + b1[o0 + 3], 0.f);
}

// Stage 2: wgt[b,k,p] = sum_o w2[k,o] * t[b,o,p] + b2[k]
// grid (49, 196, 4), block 64. Each thread: one pixel, 4 'k' outputs.
__global__ void gen2_kernel(const float* __restrict__ t,
                            const float* __restrict__ w2,
                            const float* __restrict__ b2,
                            float* __restrict__ wgt) {
    const int p  = blockIdx.x * 64 + threadIdx.x;
    const int k0 = blockIdx.y * 4;
    const int b  = blockIdx.z;
    const float* tb = t + (size_t)b * RED_ * HW_ + p;
    const float* w2a = w2 + (size_t)(k0 + 0) * RED_;
    const float* w2b = w2 + (size_t)(k0 + 1) * RED_;
    const float* w2c = w2 + (size_t)(k0 + 2) * RED_;
    const float* w2d = w2 + (size_t)(k0 + 3) * RED_;
    float a0 = b2[k0 + 0], a1 = b2[k0 + 1], a2 = b2[k0 + 2], a3 = b2[k0 + 3];
#pragma unroll 8
    for (int o = 0; o < RED_; ++o) {
        const float tv = tb[(size_t)o * HW_];
        a0 += w2a[o] * tv;
        a1 += w2b[o] * tv;
        a2 += w2c[o] * tv;
        a3 += w2d[o] * tv;
    }
    float* wb = wgt + ((size_t)b * KG_ + k0) * HW_ + p;
    wb[0 * HW_] = a0;
    wb[1 * HW_] = a1;
    wb[2 * HW_] = a2;
    wb[3 * HW_] = a3;
}

// Stage 3: out[b, g*16+c, h, w] =
//   sum_{kh,kw} wgt[b, g*49 + kh*7+kw, h, w] * x[b, g*16+c, h-3+kh, w-3+kw]
// grid (14, 16, 4), block 256 (64 lanes over w, 4 rows of h per block).
// Each thread caches its 49 per-pixel filter taps in registers, reuses across
// the 16 channels of the group.
__global__ void inv_kernel(const float* __restrict__ x,
                           const float* __restrict__ wgt,
                           float* __restrict__ out) {
    const int tid = threadIdx.x;
    const int w   = tid & 63;
    const int dh  = tid >> 6;
    const int h   = blockIdx.x * 4 + dh;
    const int g   = blockIdx.y;
    const int b   = blockIdx.z;
    if (w >= W_) return;

    float wv[KK_];
    const float* wp = wgt + ((size_t)b * KG_ + (size_t)g * KK_) * HW_ + h * W_ + w;
#pragma unroll
    for (int k = 0; k < KK_; ++k) wv[k] = wp[(size_t)k * HW_];

    const float* xb = x + ((size_t)b * C_ + (size_t)g * GC_) * HW_;
    float* ob = out + ((size_t)b * C_ + (size_t)g * GC_) * HW_ + h * W_ + w;

    for (int c = 0; c < GC_; ++c) {
        float acc = 0.f;
        const float* xc = xb + (size_t)c * HW_;
#pragma unroll
        for (int kh = 0; kh < Kk; ++kh) {
            const int hy = h + kh - 3;
            if (hy < 0 || hy >= H_) continue;
#pragma unroll
            for (int kw = 0; kw < Kk; ++kw) {
                const int wx = w + kw - 3;
                if (wx < 0 || wx >= W_) continue;
                acc += wv[kh * 7 + kw] * xc[hy * W_ + wx];
            }
        }
        ob[(size_t)c * HW_] = acc;
    }
}

extern "C" void kernel_launch(void* const* d_in, const int* in_sizes, int n_in,
                              void* d_out, int out_size, void* d_ws, size_t ws_size,
                              hipStream_t stream) {
    const float* x  = (const float*)d_in[0];
    const float* w1 = (const float*)d_in[1];
    const float* b1 = (const float*)d_in[2];
    const float* w2 = (const float*)d_in[3];
    const float* b2 = (const float*)d_in[4];
    float* out = (float*)d_out;

    // workspace layout: t (4*64*3136 f32 = 3.2 MB), wgt (4*784*3136 f32 = 39.3 MB)
    float* t   = (float*)d_ws;
    float* wgt = t + (size_t)B_ * RED_ * HW_;

    gen1_kernel<<<dim3(HW_ / 64, RED_ / 4, B_), 64, 0, stream>>>(x, w1, b1, t);
    gen2_kernel<<<dim3(HW_ / 64, KG_ / 4, B_), 64, 0, stream>>>(t, w2, b2, wgt);
    inv_kernel <<<dim3(H_ / 4, G_, B_),       256, 0, stream>>>(x, wgt, out);
}

// Round 2
// 162.548 us; speedup vs baseline: 1.3827x; 1.3827x over previous
//
#include <hip/hip_runtime.h>

#define B_    4
#define C_    256
#define Kk    7
#define GC_   16
#define G_    16
#define RED_  64
#define H_    56
#define W_    56
#define HW_   (H_ * W_)      // 3136
#define KK_   49
#define KG_   784            // K*K*G
#define HP_   62             // padded rows  (56 + 3 + 3)
#define WP_   64             // padded cols  (56 + 3 + 3 -> 64 for alignment)
#define NQ_   784            // float4-quads per (b,g) image plane: 3136/4

typedef float f4 __attribute__((ext_vector_type(4)));

__device__ __forceinline__ f4 ld4(const float* p) { return *(const f4*)p; }
__device__ __forceinline__ void st4(float* p, f4 v) { *(f4*)p = v; }

// ---------------------------------------------------------------------------
// Pad x -> xp[b][c][62][64], zero halo of 3 (cols padded to 64 for alignment).
// total elems = 4*256*62*64 = 4,063,232 = 15872 * 256
__global__ __launch_bounds__(256) void pad_kernel(const float* __restrict__ x,
                                                  float* __restrict__ xp) {
    const int idx  = blockIdx.x * 256 + threadIdx.x;
    const int wp   = idx & 63;
    const int rest = idx >> 6;
    const int hp   = rest % HP_;
    const int bc   = rest / HP_;
    const int h = hp - 3, w = wp - 3;
    float v = 0.f;
    if (h >= 0 && h < H_ && w >= 0 && w < W_)
        v = x[(size_t)bc * HW_ + h * W_ + w];
    xp[idx] = v;
}

// ---------------------------------------------------------------------------
// Stage 1: t[b,o,p] = relu( sum_c w1[o,c]*x[b,c,p] + b1[o] )
// thread = 4 pixels x 4 outputs. grid (13, 16), block 256. q < 3136 masked.
__global__ __launch_bounds__(256) void gen1_kernel(const float* __restrict__ x,
                                                   const float* __restrict__ w1,
                                                   const float* __restrict__ b1,
                                                   float* __restrict__ t) {
    const int q = blockIdx.x * 256 + threadIdx.x;   // quad over [b][p]
    if (q >= B_ * NQ_) return;
    const int b  = q / NQ_;
    const int p0 = (q - b * NQ_) * 4;
    const int o0 = blockIdx.y * 4;                  // uniform -> scalar w1 loads
    const float* xb = x + (size_t)b * C_ * HW_ + p0;
    const float* wr0 = w1 + (size_t)(o0 + 0) * C_;
    const float* wr1 = w1 + (size_t)(o0 + 1) * C_;
    const float* wr2 = w1 + (size_t)(o0 + 2) * C_;
    const float* wr3 = w1 + (size_t)(o0 + 3) * C_;
    f4 a0 = 0.f, a1 = 0.f, a2 = 0.f, a3 = 0.f;
#pragma unroll 8
    for (int c = 0; c < C_; ++c) {
        const f4 xv = ld4(xb + (size_t)c * HW_);
        a0 += wr0[c] * xv;
        a1 += wr1[c] * xv;
        a2 += wr2[c] * xv;
        a3 += wr3[c] * xv;
    }
    a0 += b1[o0 + 0]; a1 += b1[o0 + 1]; a2 += b1[o0 + 2]; a3 += b1[o0 + 3];
#pragma unroll
    for (int j = 0; j < 4; ++j) {
        a0[j] = fmaxf(a0[j], 0.f); a1[j] = fmaxf(a1[j], 0.f);
        a2[j] = fmaxf(a2[j], 0.f); a3[j] = fmaxf(a3[j], 0.f);
    }
    float* tb = t + ((size_t)b * RED_ + o0) * HW_ + p0;
    st4(tb + 0 * HW_, a0); st4(tb + 1 * HW_, a1);
    st4(tb + 2 * HW_, a2); st4(tb + 3 * HW_, a3);
}

// ---------------------------------------------------------------------------
// Stage 2: wgt[b,k,p] = sum_o w2[k,o]*t[b,o,p] + b2[k]
// thread = 4 pixels x 16 k. grid (13, 49), block 256.
__global__ __launch_bounds__(256) void gen2_kernel(const float* __restrict__ t,
                                                   const float* __restrict__ w2,
                                                   const float* __restrict__ b2,
                                                   float* __restrict__ wgt) {
    const int q = blockIdx.x * 256 + threadIdx.x;
    if (q >= B_ * NQ_) return;
    const int b  = q / NQ_;
    const int p0 = (q - b * NQ_) * 4;
    const int k0 = blockIdx.y * 16;                 // uniform -> scalar w2 loads
    const float* tb = t + (size_t)b * RED_ * HW_ + p0;
    f4 acc[16];
#pragma unroll
    for (int i = 0; i < 16; ++i) acc[i] = b2[k0 + i];
#pragma unroll 4
    for (int o = 0; o < RED_; ++o) {
        const f4 tv = ld4(tb + (size_t)o * HW_);
#pragma unroll
        for (int i = 0; i < 16; ++i)
            acc[i] += w2[(size_t)(k0 + i) * RED_ + o] * tv;
    }
    float* wb = wgt + ((size_t)b * KG_ + k0) * HW_ + p0;
#pragma unroll
    for (int i = 0; i < 16; ++i) st4(wb + (size_t)i * HW_, acc[i]);
}

// ---------------------------------------------------------------------------
// Stage 3 (involution): thread = 4 pixels x 4 channels.
// lane = qi*4 + cs  (16 quads x 4 channel-subsets per wave -> tap loads
// broadcast across the 4 cs-lanes, no redundant wgt traffic).
// grid (13, 16 g, 4 b), block 256 (4 waves, 64 quads per block).
__global__ __launch_bounds__(256) void inv_kernel(const float* __restrict__ xp,
                                                  const float* __restrict__ wgt,
                                                  float* __restrict__ out) {
    const int tid  = threadIdx.x;
    const int wave = tid >> 6;
    const int qi   = (tid & 63) >> 2;
    const int cs   = tid & 3;
    const int q    = blockIdx.x * 64 + wave * 16 + qi;  // image-local quad
    if (q >= NQ_) return;
    const int c0 = cs * 4;
    const int g  = blockIdx.y;
    const int b  = blockIdx.z;
    const int p0  = q * 4;
    const int row = q / 14;            // p0 / 56   (56 = 4*14)
    const int w0  = (q % 14) * 4;

    const float* wb = wgt + ((size_t)b * KG_ + (size_t)g * KK_) * HW_ + p0;
    const float* xb = xp + (size_t)(b * C_ + g * GC_ + c0) * HP_ * WP_;

    f4 acc[4] = {f4(0.f), f4(0.f), f4(0.f), f4(0.f)};   // acc[ci][j]

#pragma unroll
    for (int kh = 0; kh < Kk; ++kh) {
        f4 tp[Kk];
#pragma unroll
        for (int kw = 0; kw < Kk; ++kw)
            tp[kw] = ld4(wb + (size_t)(kh * 7 + kw) * HW_);
        const int hp = row + kh;                        // padded row index
#pragma unroll
        for (int ci = 0; ci < 4; ++ci) {
            const float* xr = xb + ((size_t)ci * HP_ + hp) * WP_ + w0;
            const f4 x0 = ld4(xr), x1 = ld4(xr + 4), x2 = ld4(xr + 8);
            float xs[12];
#pragma unroll
            for (int j = 0; j < 4; ++j) {
                xs[j] = x0[j]; xs[4 + j] = x1[j]; xs[8 + j] = x2[j];
            }
#pragma unroll
            for (int kw = 0; kw < Kk; ++kw)
#pragma unroll
                for (int j = 0; j < 4; ++j)
                    acc[ci][j] += tp[kw][j] * xs[j + kw];
        }
    }

    float* ob = out + (size_t)(b * C_ + g * GC_ + c0) * HW_ + p0;
#pragma unroll
    for (int ci = 0; ci < 4; ++ci) st4(ob + (size_t)ci * HW_, acc[ci]);
}

// ---------------------------------------------------------------------------
extern "C" void kernel_launch(void* const* d_in, const int* in_sizes, int n_in,
                              void* d_out, int out_size, void* d_ws, size_t ws_size,
                              hipStream_t stream) {
    const float* x  = (const float*)d_in[0];
    const float* w1 = (const float*)d_in[1];
    const float* b1 = (const float*)d_in[2];
    const float* w2 = (const float*)d_in[3];
    const float* b2 = (const float*)d_in[4];
    float* out = (float*)d_out;

    // ws layout: xp (16.25 MB) | t (3.2 MB) | wgt (39.3 MB)  = 58.8 MB
    float* xp  = (float*)d_ws;
    float* t   = xp + (size_t)B_ * C_ * HP_ * WP_;
    float* wgt = t  + (size_t)B_ * RED_ * HW_;

    pad_kernel <<<dim3((B_ * C_ * HP_ * WP_) / 256), 256, 0, stream>>>(x, xp);
    gen1_kernel<<<dim3(13, RED_ / 4),      256, 0, stream>>>(x, w1, b1, t);
    gen2_kernel<<<dim3(13, KG_ / 16),      256, 0, stream>>>(t, w2, b2, wgt);
    inv_kernel <<<dim3(13, G_, B_),        256, 0, stream>>>(xp, wgt, out);
}

// Round 3
// 155.537 us; speedup vs baseline: 1.4450x; 1.0451x over previous
//
#include <hip/hip_runtime.h>

#define B_    4
#define C_    256
#define Kk    7
#define GC_   16
#define G_    16
#define RED_  64
#define H_    56
#define W_    56
#define HW_   (H_ * W_)      // 3136
#define KK_   49
#define KG_   784            // K*K*G
#define HP_   62             // padded rows
#define WP_   64             // padded cols
#define NP_   (B_ * HW_)     // 12544 global pixels
#define NQ_   784            // quads per (b,g) plane

typedef float  f4    __attribute__((ext_vector_type(4)));
typedef float  f2    __attribute__((ext_vector_type(2)));
typedef float  f32x4 __attribute__((ext_vector_type(4)));
typedef __bf16 bf16x8 __attribute__((ext_vector_type(8)));
typedef __bf16 bf16x4 __attribute__((ext_vector_type(4)));
typedef unsigned short u16;
typedef u16    u16x4 __attribute__((ext_vector_type(4)));

__device__ __forceinline__ f4 ld4(const float* p) { return *(const f4*)p; }
__device__ __forceinline__ void st4(float* p, f4 v) { *(f4*)p = v; }
__device__ __forceinline__ float bf2f(u16 u) {
    return __uint_as_float(((unsigned)u) << 16);
}
__device__ __forceinline__ bf16x8 pack8(f4 lo, f4 hi) {
    bf16x8 r;
    r[0] = (__bf16)lo[0]; r[1] = (__bf16)lo[1]; r[2] = (__bf16)lo[2]; r[3] = (__bf16)lo[3];
    r[4] = (__bf16)hi[0]; r[5] = (__bf16)hi[1]; r[6] = (__bf16)hi[2]; r[7] = (__bf16)hi[3];
    return r;
}

// ---------------------------------------------------------------------------
// Pad x -> xp[b][c][62][64] f32, zero halo of 3.
__global__ __launch_bounds__(256) void pad_kernel(const float* __restrict__ x,
                                                  float* __restrict__ xp) {
    const int idx  = blockIdx.x * 256 + threadIdx.x;
    const int wp   = idx & 63;
    const int rest = idx >> 6;
    const int hp   = rest % HP_;
    const int bc   = rest / HP_;
    const int h = hp - 3, w = wp - 3;
    float v = 0.f;
    if (h >= 0 && h < H_ && w >= 0 && w < W_)
        v = x[(size_t)bc * HW_ + h * W_ + w];
    xp[idx] = v;
}

// ---------------------------------------------------------------------------
// gen1: t[P][64] bf16 = relu(w1 @ x + b1).  P = b*3136 + p (pixel-major, K=o contiguous)
// grid (98, 4), block 256 = 4 waves; wave -> o-group of 4; lane -> pixel pair.
__global__ __launch_bounds__(256) void gen1_kernel(const float* __restrict__ x,
                                                   const float* __restrict__ w1,
                                                   const float* __restrict__ b1,
                                                   __bf16* __restrict__ t) {
    const int lane = threadIdx.x & 63;
    const int wave = threadIdx.x >> 6;
    const int o0   = __builtin_amdgcn_readfirstlane((blockIdx.y * 4 + wave) * 4);
    const int P0   = blockIdx.x * 128 + lane * 2;          // pixel pair (never crosses b)
    const int b    = P0 / HW_;
    const int p    = P0 - b * HW_;
    const float* xb = x + (size_t)b * C_ * HW_ + p;
    const float* wr = w1 + (size_t)o0 * C_;

    f2 a0 = 0.f, a1 = 0.f, a2 = 0.f, a3 = 0.f;
#pragma unroll 8
    for (int c = 0; c < C_; ++c) {
        const f2 xv = *(const f2*)(xb + (size_t)c * HW_);
        a0 += wr[c] * xv;
        a1 += wr[C_ + c] * xv;
        a2 += wr[2 * C_ + c] * xv;
        a3 += wr[3 * C_ + c] * xv;
    }
    a0 += b1[o0 + 0]; a1 += b1[o0 + 1]; a2 += b1[o0 + 2]; a3 += b1[o0 + 3];
#pragma unroll
    for (int j = 0; j < 2; ++j) {
        bf16x4 pk;
        pk[0] = (__bf16)fmaxf(a0[j], 0.f);
        pk[1] = (__bf16)fmaxf(a1[j], 0.f);
        pk[2] = (__bf16)fmaxf(a2[j], 0.f);
        pk[3] = (__bf16)fmaxf(a3[j], 0.f);
        *(bf16x4*)(t + (size_t)(P0 + j) * RED_ + o0) = pk;
    }
}

// ---------------------------------------------------------------------------
// gen2 (MFMA bf16): wgt[b][784][3136] bf16 = w2 @ t + b2
// A = w2 [784 x 64] (cvt f32->bf16 inline), B = t [P][64] bf16.
// grid (49 ptiles of 256, 49 ktiles of 16), block 256 = 4 waves on pixels.
// Wave: 16 k-rows x 64 pixels = 2 ksteps x 4 colgroups = 8 MFMA.
__global__ __launch_bounds__(256) void gen2_mfma(const __bf16* __restrict__ t,
                                                 const float* __restrict__ w2,
                                                 const float* __restrict__ b2,
                                                 __bf16* __restrict__ wgt) {
    const int lane = threadIdx.x & 63;
    const int wave = threadIdx.x >> 6;
    const int k0   = blockIdx.y * 16;
    const int P0   = __builtin_amdgcn_readfirstlane(blockIdx.x * 256 + wave * 64);
    const int b    = P0 / HW_;                  // 64-px chunk never crosses b (3136 = 49*64)
    const int row  = lane & 15;                 // A row (k-row) / B,D col (pixel)
    const int kg   = lane >> 4;                 // k-subgroup: k = kg*8 + j

    // A fragments (k-rows k0+row, K = 0..63)
    const float* w2r = w2 + (size_t)(k0 + row) * RED_ + kg * 8;
    const bf16x8 a0 = pack8(ld4(w2r), ld4(w2r + 4));
    const bf16x8 a1 = pack8(ld4(w2r + 32), ld4(w2r + 36));

    f32x4 acc[4] = {f32x4(0.f), f32x4(0.f), f32x4(0.f), f32x4(0.f)};
#pragma unroll
    for (int cg = 0; cg < 4; ++cg) {
        const __bf16* tp = t + (size_t)(P0 + cg * 16 + row) * RED_ + kg * 8;
        const bf16x8 bv0 = *(const bf16x8*)tp;
        const bf16x8 bv1 = *(const bf16x8*)(tp + 32);
        acc[cg] = __builtin_amdgcn_mfma_f32_16x16x32_bf16(a0, bv0, acc[cg], 0, 0, 0);
        acc[cg] = __builtin_amdgcn_mfma_f32_16x16x32_bf16(a1, bv1, acc[cg], 0, 0, 0);
    }

    // epilogue: D row (k) = k0 + kg*4 + j, col (pixel) = P0 + cg*16 + (lane&15)
    float bias[4];
#pragma unroll
    for (int j = 0; j < 4; ++j) bias[j] = b2[k0 + kg * 4 + j];
#pragma unroll
    for (int cg = 0; cg < 4; ++cg) {
        const int P = P0 + cg * 16 + row;
        const int p = P - b * HW_;
#pragma unroll
        for (int j = 0; j < 4; ++j) {
            const int krow = k0 + kg * 4 + j;
            wgt[((size_t)b * KG_ + krow) * HW_ + p] = (__bf16)(acc[cg][j] + bias[j]);
        }
    }
}

// ---------------------------------------------------------------------------
// inv: out[b, g*16+c, p] = sum_k wgt_bf16[b, g*49+k, p] * xp[b, g*16+c, shifted p]
// thread = 1 quad (4 px) x 2 channels. grid (13, 16 g, 8 = b*2 + chhalf), block 256.
__global__ __launch_bounds__(256) void inv_kernel(const float* __restrict__ xp,
                                                  const u16* __restrict__ wgt,
                                                  float* __restrict__ out) {
    const int tid  = threadIdx.x;
    const int wave = tid >> 6;
    const int qi   = (tid & 63) >> 2;
    const int cs   = tid & 3;
    const int q    = blockIdx.x * 64 + wave * 16 + qi;
    if (q >= NQ_) return;
    const int g    = blockIdx.y;
    const int z    = blockIdx.z;
    const int b    = z >> 1;
    const int c0   = (z & 1) * 8 + cs * 2;       // 2 channels per thread
    const int p0   = q * 4;
    const int rowp = q / 14;
    const int w0   = (q % 14) * 4;

    const u16* wb   = wgt + ((size_t)b * KG_ + (size_t)g * KK_) * HW_ + p0;
    const float* xb = xp + ((size_t)(b * C_ + g * GC_ + c0)) * HP_ * WP_;

    f4 acc0 = 0.f, acc1 = 0.f;

#pragma unroll
    for (int kh = 0; kh < Kk; ++kh) {
        float tp[Kk][4];
#pragma unroll
        for (int kw = 0; kw < Kk; ++kw) {
            const u16x4 tv = *(const u16x4*)(wb + (size_t)(kh * 7 + kw) * HW_);
#pragma unroll
            for (int j = 0; j < 4; ++j) tp[kw][j] = bf2f(tv[j]);
        }
        const int hp = rowp + kh;
#pragma unroll
        for (int ci = 0; ci < 2; ++ci) {
            const float* xr = xb + ((size_t)ci * HP_ + hp) * WP_ + w0;
            const f4 x0 = ld4(xr), x1 = ld4(xr + 4), x2 = ld4(xr + 8);
            float xs[12];
#pragma unroll
            for (int j = 0; j < 4; ++j) {
                xs[j] = x0[j]; xs[4 + j] = x1[j]; xs[8 + j] = x2[j];
            }
#pragma unroll
            for (int kw = 0; kw < Kk; ++kw) {
#pragma unroll
                for (int j = 0; j < 4; ++j) {
                    if (ci == 0) acc0[j] += tp[kw][j] * xs[j + kw];
                    else         acc1[j] += tp[kw][j] * xs[j + kw];
                }
            }
        }
    }

    float* ob = out + ((size_t)(b * C_ + g * GC_ + c0)) * HW_ + p0;
    st4(ob, acc0);
    st4(ob + HW_, acc1);
}

// ---------------------------------------------------------------------------
extern "C" void kernel_launch(void* const* d_in, const int* in_sizes, int n_in,
                              void* d_out, int out_size, void* d_ws, size_t ws_size,
                              hipStream_t stream) {
    const float* x  = (const float*)d_in[0];
    const float* w1 = (const float*)d_in[1];
    const float* b1 = (const float*)d_in[2];
    const float* w2 = (const float*)d_in[3];
    const float* b2 = (const float*)d_in[4];
    float* out = (float*)d_out;

    // ws layout: xp f32 (16.25 MB) | t bf16 (1.6 MB) | wgt bf16 (19.7 MB)
    char* ws = (char*)d_ws;
    float*  xp  = (float*)ws;
    __bf16* t   = (__bf16*)(ws + (size_t)B_ * C_ * HP_ * WP_ * 4);
    __bf16* wgt = (__bf16*)(ws + (size_t)B_ * C_ * HP_ * WP_ * 4 + (size_t)NP_ * RED_ * 2);

    pad_kernel<<<dim3((B_ * C_ * HP_ * WP_) / 256), 256, 0, stream>>>(x, xp);
    gen1_kernel<<<dim3(NP_ / 128, 4), 256, 0, stream>>>(x, w1, b1, t);
    gen2_mfma<<<dim3(NP_ / 256, KG_ / 16), 256, 0, stream>>>(t, w2, b2, wgt);
    inv_kernel<<<dim3(13, G_, 8), 256, 0, stream>>>(xp, (const u16*)wgt, out);
}